// Round 16
// baseline (777.420 us; speedup 1.0000x reference)
//
#include <hip/hip_runtime.h>
#include <cstddef>

// ---- problem constants ----
#define NN     50000
#define NE     800000
#define IND    128
#define EMBD   64
#define IN1    192     // IND + EMBD
#define HDIM   256
#define RR     12
#define BB     8
#define NGENE  20000
#define NPATH  2000
#define NRK    (RR * NN)               // 600000 segment keys (dst-major: dst*RR+rel)
#define SCB    1024
#define NSB    ((NRK + SCB - 1) / SCB) // 586
#define CH0    25088                   // conv2 fallback chunk0 rows [0,CH0)

typedef __attribute__((ext_vector_type(8))) short short8;
typedef __attribute__((ext_vector_type(4))) float f32x4;
typedef unsigned short ushortT;
typedef __attribute__((address_space(3))) void lds_void;
typedef __attribute__((address_space(1))) const void glb_void;

__device__ __forceinline__ float bu2f(unsigned short u) {
  unsigned int x = ((unsigned int)u) << 16;
  return __builtin_bit_cast(float, x);
}
__device__ __forceinline__ unsigned short f2bu(float f) {
  unsigned int x = __builtin_bit_cast(unsigned int, f);
  unsigned int r = (x + 0x7fffu + ((x >> 16) & 1u)) >> 16;
  return (unsigned short)r;
}

// Global A-layout swizzle: within each 64-elem k-group, 8-elem chunk ch of row g
// is stored at chunk position ch ^ (g & 7). GEMM DMA-stages raw row slices, so the
// LDS tile arrives pre-swizzled (conflict-free ds_read_b128 frag loads).

// ---------- build x0 = [x | 0] bf16, swizzled ----------
__global__ void k_build_x0(const float* __restrict__ x, ushortT* __restrict__ x0) {
  int t = blockIdx.x * 256 + threadIdx.x;
  if (t >= NN * IN1) return;
  int n = t / IN1, i = t - n * IN1;
  float v = (i < IND) ? x[(size_t)n * IND + i] : 0.0f;
  int kt = i >> 6, ch = (i >> 3) & 7, off = i & 7;
  x0[(size_t)n * IN1 + kt * 64 + ((ch ^ (n & 7)) * 8) + off] = f2bu(v);
}

__global__ void k_add_emb(const int* __restrict__ idx, const float* __restrict__ emb,
                          ushortT* __restrict__ x0, int count) {
  int t = blockIdx.x * 256 + threadIdx.x;
  if (t >= count * EMBD) return;
  int g = t / EMBD, j = t - g * EMBD;
  int n = idx[g];
  int ch = (j >> 3) & 7, off = j & 7;
  x0[(size_t)n * IN1 + 128 + ((ch ^ (n & 7)) * 8) + off] = f2bu(emb[t]);
}

// ---------- per-(dst,rel) edge counts (dst-major keys) ----------
__global__ void k_count(const int* __restrict__ ei, const int* __restrict__ et,
                        int* __restrict__ cnt) {
  int e = blockIdx.x * 256 + threadIdx.x;
  if (e >= NE) return;
  atomicAdd(&cnt[ei[NE + e] * RR + et[e]], 1);
}

// ---------- 3-kernel exclusive scan ----------
__global__ __launch_bounds__(256) void k_scan1(const int* __restrict__ cnt,
                                               int* __restrict__ bsum) {
  __shared__ int lds[256];
  int t = threadIdx.x;
  int base = blockIdx.x * SCB + t * 4;
  int s = 0;
#pragma unroll
  for (int j = 0; j < 4; j++) { int idx = base + j; if (idx < NRK) s += cnt[idx]; }
  lds[t] = s; __syncthreads();
  for (int d = 128; d > 0; d >>= 1) { if (t < d) lds[t] += lds[t + d]; __syncthreads(); }
  if (t == 0) bsum[blockIdx.x] = lds[0];
}

__global__ __launch_bounds__(1024) void k_scan2(const int* __restrict__ bsum,
                                                int* __restrict__ bscan) {
  __shared__ int lds[1024];
  int t = threadIdx.x;
  int v = (t < NSB) ? bsum[t] : 0;
  lds[t] = v; __syncthreads();
  for (int d = 1; d < 1024; d <<= 1) {
    int add = (t >= d) ? lds[t - d] : 0; __syncthreads();
    lds[t] += add; __syncthreads();
  }
  if (t < NSB) bscan[t] = lds[t] - v;
}

__global__ __launch_bounds__(256) void k_scan3(const int* __restrict__ cnt,
                                               const int* __restrict__ bscan,
                                               int* __restrict__ off) {
  __shared__ int lds[256];
  int t = threadIdx.x;
  int base = blockIdx.x * SCB + t * 4;
  int v[4]; int s = 0;
#pragma unroll
  for (int j = 0; j < 4; j++) { int idx = base + j; v[j] = (idx < NRK) ? cnt[idx] : 0; s += v[j]; }
  lds[t] = s; __syncthreads();
  for (int d = 1; d < 256; d <<= 1) {
    int add = (t >= d) ? lds[t - d] : 0; __syncthreads();
    lds[t] += add; __syncthreads();
  }
  int ex = lds[t] - s + bscan[blockIdx.x];
#pragma unroll
  for (int j = 0; j < 4; j++) {
    int idx = base + j;
    if (idx < NRK) { off[idx] = ex; ex += v[j]; }
  }
}

__global__ void k_fill(const int* __restrict__ ei, const int* __restrict__ et,
                       const int* __restrict__ off, int* __restrict__ fill,
                       int* __restrict__ srcs) {
  int e = blockIdx.x * 256 + threadIdx.x;
  if (e >= NE) return;
  int key = ei[NE + e] * RR + et[e];
  int pos = off[key] + atomicAdd(&fill[key], 1);
  srcs[pos] = ei[e];
}

// ---------- Wb[b][o][i] = bf16(basis[b,i,o]) (linear layout, follows root seg) ----------
__global__ void k_wbasis(const float* __restrict__ basis, ushortT* __restrict__ W,
                         int in_dim) {
  int t = blockIdx.x * 256 + threadIdx.x;
  int total = BB * HDIM * in_dim;
  if (t >= total) return;
  int i = t % in_dim;
  int o = (t / in_dim) & 255;
  int b = t / (in_dim * 256);
  W[t] = f2bu(basis[((size_t)b * in_dim + i) * HDIM + o]);
}

__global__ void k_troot(const float* __restrict__ root, ushortT* __restrict__ rt,
                        int in_dim) {
  int t = blockIdx.x * 256 + threadIdx.x;
  if (t >= in_dim * HDIM) return;
  int i = t % in_dim, o = t / in_dim;
  rt[t] = f2bu(root[(size_t)i * HDIM + o]);
}

// ---------- basis-space aggregation: one wave per dst (round-10 proven version) ----
// Batched first-2-edges gather (24 independent loads), serial >=3-edge tails.
__global__ __launch_bounds__(256) void k_aggb(const int* __restrict__ srcs,
                                              const int* __restrict__ off,
                                              const int* __restrict__ cnt,
                                              const float* __restrict__ comp,
                                              const ushortT* __restrict__ xin,
                                              ushortT* __restrict__ aggB,
                                              int in_dim, int row0, int nrows) {
  int wv = threadIdx.x >> 6;
  int lane = threadIdx.x & 63;
  int li = blockIdx.x * 4 + wv;          // chunk-local dst index
  if (li >= nrows) return;
  int dst = row0 + li;
  bool act = lane * 4 < in_dim;
  int kt = lane >> 4, chl = (lane >> 1) & 7, offh = (lane & 1) * 4;
  int kbase = kt * 64 + offh;

  auto gaddr = [&](int s) {
    return (const ushort4*)(xin + (size_t)s * in_dim + kbase + ((chl ^ (s & 7)) * 8));
  };

  int beg[RR], n[RR];
#pragma unroll
  for (int rl = 0; rl < RR; rl++) {
    beg[rl] = off[dst * RR + rl];
    n[rl]   = cnt[dst * RR + rl];
  }

  int sa[RR], sb[RR];
#pragma unroll
  for (int rl = 0; rl < RR; rl++) {
    sa[rl] = (n[rl] > 0) ? srcs[beg[rl]] : 0;
    sb[rl] = (n[rl] > 1) ? srcs[beg[rl] + 1] : 0;
  }

  ushort4 va[RR], vb[RR];
  if (act) {
#pragma unroll
    for (int rl = 0; rl < RR; rl++) va[rl] = *gaddr(sa[rl]);
#pragma unroll
    for (int rl = 0; rl < RR; rl++) vb[rl] = *gaddr(sb[rl]);
  }

  float acc[BB][4];
#pragma unroll
  for (int b = 0; b < BB; b++)
#pragma unroll
    for (int e = 0; e < 4; e++) acc[b][e] = 0.f;

#pragma unroll
  for (int rl = 0; rl < RR; rl++) {
    int ne = n[rl];
    if (ne == 0) continue;
    float s0 = 0.f, s1 = 0.f, s2 = 0.f, s3 = 0.f;
    if (act) {
      s0 = bu2f(va[rl].x); s1 = bu2f(va[rl].y); s2 = bu2f(va[rl].z); s3 = bu2f(va[rl].w);
      if (ne > 1) {
        s0 += bu2f(vb[rl].x); s1 += bu2f(vb[rl].y);
        s2 += bu2f(vb[rl].z); s3 += bu2f(vb[rl].w);
      }
    }
    for (int p = 2; p < ne; p++) {          // rare tail (~15% of relations)
      int s = srcs[beg[rl] + p];
      if (act) {
        ushort4 v = *gaddr(s);
        s0 += bu2f(v.x); s1 += bu2f(v.y); s2 += bu2f(v.z); s3 += bu2f(v.w);
      }
    }
    float wn = 1.0f / (float)ne;
#pragma unroll
    for (int b = 0; b < BB; b++) {
      float cb = comp[rl * BB + b] * wn;
      acc[b][0] += cb * s0; acc[b][1] += cb * s1;
      acc[b][2] += cb * s2; acc[b][3] += cb * s3;
    }
  }

  if (act) {
    size_t base = (size_t)li * BB * in_dim;
    int swz = (chl ^ (dst & 7)) * 8;
#pragma unroll
    for (int b = 0; b < BB; b++) {
      ushort4 o;
      o.x = f2bu(acc[b][0]); o.y = f2bu(acc[b][1]);
      o.z = f2bu(acc[b][2]); o.w = f2bu(acc[b][3]);
      *(ushort4*)(aggB + base + (size_t)b * in_dim + kbase + swz) = o;
    }
  }
}

// ---------- single-pass 9-segment MFMA GEMM, 64x256 tile ----------
// 256 threads = 4 waves, wave wc owns cols [wc*64,wc*64+64) (== head wc), 64 rows.
// W fragments REGISTER-double-buffered, loaded one tile ahead at the TOP of the
// iteration; wait is vmcnt(10). Never vmcnt(0) in the loop.
// Duration is per-DISPATCH latency-bound: at 392 blocks both K=27 and K=36
// measure 87us; at 782 blocks K=27 measures 122.7us (r15) -- so full-graph
// single dispatches beat chunked pairs. LDS 33.8KB -> 4 blocks/CU max; 782
// blocks = 3.05/CU, fully co-resident.
__global__ __launch_bounds__(256, 2) void k_gemm(const ushortT* __restrict__ xin,
                                                 const ushortT* __restrict__ aggB,
                                                 const ushortT* __restrict__ W,
                                                 const float* __restrict__ bias,
                                                 const float* __restrict__ att,
                                                 ushortT* __restrict__ hout,
                                                 int in_dim, int row0, int row1) {
  __shared__ ushortT As[4][64 * 64];
  __shared__ float sm[64][4];
  const int tid = threadIdx.x;
  const int bm = row0 + blockIdx.x * 64;
  const int wv = tid >> 6, l = tid & 63;
  const int wc = wv;                       // head / col-group
  const int lm = l & 15, lq = l >> 4;
  const int nkt = in_dim >> 6;
  const int totKt = 9 * nkt;

  f32x4 acc[4][4];
#pragma unroll
  for (int mt = 0; mt < 4; mt++)
#pragma unroll
    for (int nt = 0; nt < 4; nt++) acc[mt][nt] = (f32x4){0.f, 0.f, 0.f, 0.f};

  struct WF { short8 f[2][4]; };           // [ks][nt], all indices compile-time
  WF w0, w1;

  auto stage = [&](int buf, int seg, int kt) {
#pragma unroll
    for (int j = 0; j < 2; j++) {
      int r = wv * 16 + j * 8;                 // wave-uniform LDS row base
      int g = bm + r + (l >> 3); if (g >= row1) g = row1 - 1;
      const ushortT* gp;
      if (seg == 0) gp = xin + (size_t)g * in_dim + kt * 64 + (l & 7) * 8;
      else gp = aggB + ((size_t)(g - row0) * 8 + (seg - 1)) * in_dim + kt * 64 + (l & 7) * 8;
      ushortT* lp = &As[buf][r * 64];
      __builtin_amdgcn_global_load_lds((glb_void*)gp, (lds_void*)lp, 16, 0, 0);
    }
  };

  auto loadW = [&](WF& wd, int seg, int kt) {
    const ushortT* wt = W + (size_t)(wc * 64 + lm) * in_dim +
                        (size_t)seg * 256 * in_dim + kt * 64 + lq * 8;
#pragma unroll
    for (int nt = 0; nt < 4; nt++) {
      wd.f[0][nt] = *(const short8*)(wt + (size_t)nt * 16 * in_dim);
      wd.f[1][nt] = *(const short8*)(wt + (size_t)nt * 16 * in_dim + 32);
    }
  };

  auto mfmaT = [&](int buf, const WF& wf) {
#pragma unroll
    for (int ks = 0; ks < 2; ks++) {
      short8 af[4];
#pragma unroll
      for (int mt = 0; mt < 4; mt++) {
        int ar = mt * 16 + lm;
        af[mt] = *(const short8*)(&As[buf][ar * 64 + (((ks * 4) + lq) ^ (ar & 7)) * 8]);
      }
#pragma unroll
      for (int mt = 0; mt < 4; mt++)
#pragma unroll
        for (int nt = 0; nt < 4; nt++)
          acc[mt][nt] = __builtin_amdgcn_mfma_f32_16x16x32_bf16(af[mt], wf.f[ks][nt],
                                                                acc[mt][nt], 0, 0, 0);
    }
  };

  // tile counters with clamp-at-last (keeps vmcnt literal + issue count uniform)
  int segS = 0, ktS = 0;                   // next stage tile
  int segW = 0, ktW = 0;                   // next W tile
  auto bumpC = [&](int& s, int& k) {
    if (++k == nkt) { k = 0; if (++s == 9) { s = 8; k = nkt - 1; } }
  };

  auto body = [&](int t, WF& wuse, WF& wload) {
    loadW(wload, segW, ktW); bumpC(segW, ktW);     // W_{t+1}: FIRST issue this iter
    asm volatile("s_waitcnt vmcnt(10)" ::: "memory"); // W_t + stage_t landed
    __builtin_amdgcn_s_barrier();
    __builtin_amdgcn_sched_barrier(0);
    stage((t + 3) & 3, segS, ktS); bumpC(segS, ktS); // safe: all waves past mfma(t-1)
    mfmaT(t & 3, wuse);
  };

  // prologue: stage tiles 0,1,2; preload W tile 0
  stage(0, segS, ktS); bumpC(segS, ktS);
  stage(1, segS, ktS); bumpC(segS, ktS);
  stage(2, segS, ktS); bumpC(segS, ktS);
  loadW(w0, segW, ktW); bumpC(segW, ktW);

  int t = 0;
  for (; t + 1 < totKt; t += 2) {
    body(t, w0, w1);
    body(t + 1, w1, w0);
  }
  if (t < totKt) body(t, w0, w1);
  asm volatile("s_waitcnt vmcnt(0)" ::: "memory");
  __syncthreads();

  // ---- epilogue: bias, fused head-softmax attention, swizzled bf16 store ----
  float bv[4];
#pragma unroll
  for (int nt = 0; nt < 4; nt++) bv[nt] = bias[wc * 64 + nt * 16 + lm];
#pragma unroll
  for (int mt = 0; mt < 4; mt++)
#pragma unroll
    for (int nt = 0; nt < 4; nt++)
#pragma unroll
      for (int r = 0; r < 4; r++) acc[mt][nt][r] += bv[nt];

  float av[4];
#pragma unroll
  for (int nt = 0; nt < 4; nt++) av[nt] = att[wc * 64 + nt * 16 + lm];
#pragma unroll
  for (int mt = 0; mt < 4; mt++) {
    float sr[4];
#pragma unroll
    for (int r = 0; r < 4; r++)
      sr[r] = acc[mt][0][r] * av[0] + acc[mt][1][r] * av[1] +
              acc[mt][2][r] * av[2] + acc[mt][3][r] * av[3];
#pragma unroll
    for (int o = 1; o <= 8; o <<= 1) {
#pragma unroll
      for (int r = 0; r < 4; r++) sr[r] += __shfl_xor(sr[r], o, 64);
    }
    if (lm == 0) {
#pragma unroll
      for (int r = 0; r < 4; r++) sm[mt * 16 + lq * 4 + r][wc] = sr[r];
    }
  }
  __syncthreads();
  if (tid < 64) {
    float s0 = sm[tid][0], s1 = sm[tid][1], s2 = sm[tid][2], s3 = sm[tid][3];
    float mx = fmaxf(fmaxf(s0, s1), fmaxf(s2, s3));
    float e0 = __expf(s0 - mx), e1 = __expf(s1 - mx), e2 = __expf(s2 - mx), e3 = __expf(s3 - mx);
    float inv = 1.0f / (e0 + e1 + e2 + e3);
    sm[tid][0] = e0 * inv; sm[tid][1] = e1 * inv; sm[tid][2] = e2 * inv; sm[tid][3] = e3 * inv;
  }
  __syncthreads();
#pragma unroll
  for (int mt = 0; mt < 4; mt++) {
#pragma unroll
    for (int r = 0; r < 4; r++) {
      int rl = mt * 16 + lq * 4 + r;
      int row = bm + rl;
      if (row >= row1) continue;
      float al = sm[rl][wc];
      ushortT* op = hout + (size_t)row * HDIM + wc * 64;   // kt-group == head == wc
      int key = row & 7;
#pragma unroll
      for (int nt = 0; nt < 4; nt++) {
        int ci = nt * 16 + lm;
        op[(((ci >> 3) ^ key) * 8) + (ci & 7)] = f2bu(acc[mt][nt][r] * al);
      }
    }
  }
}

// ---------- prediction head: h is swizzled; un-swizzle on read ----------
__global__ void k_pred(const ushortT* __restrict__ h, const float* __restrict__ w,
                       const float* __restrict__ b, float* __restrict__ out) {
  int t = blockIdx.x * 256 + threadIdx.x;
  if (t >= NN * 12) return;
  int n = t / 12, j = t - n * 12;
  float acc = b[j];
  const ushortT* hp = h + (size_t)n * HDIM;
  int key = n & 7;
#pragma unroll
  for (int kt = 0; kt < 4; kt++)
#pragma unroll
    for (int cs = 0; cs < 8; cs++) {
      int ch = cs ^ key;                 // logical chunk for stored chunk cs
      int kb = kt * 64 + ch * 8;
      const ushortT* hh = hp + kt * 64 + cs * 8;
#pragma unroll
      for (int o = 0; o < 8; o++) acc += bu2f(hh[o]) * w[(kb + o) * 12 + j];
    }
  out[t] = acc;
}

extern "C" void kernel_launch(void* const* d_in, const int* in_sizes, int n_in,
                              void* d_out, int out_size, void* d_ws, size_t ws_size,
                              hipStream_t stream) {
  const float* x         = (const float*)d_in[0];
  const int*   edge_idx  = (const int*)d_in[1];
  const int*   edge_type = (const int*)d_in[2];
  const int*   gene_idx  = (const int*)d_in[3];
  const int*   path_idx  = (const int*)d_in[4];
  const float* gene_emb  = (const float*)d_in[5];
  const float* path_emb  = (const float*)d_in[6];
  const float* comp1     = (const float*)d_in[7];
  const float* basis1    = (const float*)d_in[8];
  const float* root1     = (const float*)d_in[9];
  const float* bias1     = (const float*)d_in[10];
  const float* att1      = (const float*)d_in[11];
  const float* comp2     = (const float*)d_in[12];
  const float* basis2    = (const float*)d_in[13];
  const float* root2     = (const float*)d_in[14];
  const float* bias2     = (const float*)d_in[15];
  const float* att2      = (const float*)d_in[16];
  const float* pred_w    = (const float*)d_in[17];
  const float* pred_b    = (const float*)d_in[18];
  float* out = (float*)d_out;

  // ---- dynamic workspace layout ----
  // aggB region: conv1 always uses 50000*8*192*2 = 153,600,000.
  // conv2 FULL (one dispatch) needs 50000*8*256*2 = 204,800,000 -> total 268.5 MB.
  // If ws_size is too small, fall back to the round-15 chunked conv2 (217.3 MB,
  // proven) using the same 153.6 MB region (chunk needs only 102.8 MB).
  const size_t AGG_FULL2 = (size_t)NN * BB * HDIM * 2;   // 204,800,000
  const size_t AGG_CONV1 = (size_t)NN * BB * IN1 * 2;    // 153,600,000
  const size_t TAIL      = 884736 + 1179648 + 2400000 + 2400000 + 3200000
                         + 2400000 + 4096 + 4096;        // 12,472,576
  bool full2 = ws_size >= (size_t)51200000 + AGG_FULL2 + TAIL;  // 268,472,576
  size_t aggRegion = full2 ? AGG_FULL2 : AGG_CONV1;

  char* ws = (char*)d_ws;
  ushortT* x0b   = (ushortT*)(ws);                   // 19.2 MB (h2b overlays later)
  ushortT* h2b   = (ushortT*)(ws);                   // 25.6 MB (x0b dead by then)
  ushortT* h1b   = (ushortT*)(ws + 25600000);        // 25,600,000
  ushortT* aggB  = (ushortT*)(ws + 51200000);        // aggRegion bytes
  char* tail = ws + 51200000 + aggRegion;
  ushortT* Wb1   = (ushortT*)(tail);                 // 884,736
  ushortT* Wb2   = (ushortT*)(tail + 884736);        // 1,179,648
  int*     cnt   = (int*)(tail + 2064384);           // 2,400,000
  int*     off   = (int*)(tail + 4464384);           // 2,400,000
  int*     srcs  = (int*)(tail + 6864384);           // 3,200,000
  int*     fill  = (int*)(tail + 10064384);          // 2,400,000
  int*     bsum  = (int*)(tail + 12464384);          // 4 KB
  int*     bscan = (int*)(tail + 12468480);          // 4 KB

  dim3 blk(256);

  // ---- stage 0: features + CSR build + weight prep ----
  k_build_x0<<<dim3((NN * IN1) / 256), blk, 0, stream>>>(x, x0b);
  k_add_emb<<<dim3((NGENE * EMBD) / 256), blk, 0, stream>>>(gene_idx, gene_emb, x0b, NGENE);
  k_add_emb<<<dim3((NPATH * EMBD) / 256), blk, 0, stream>>>(path_idx, path_emb, x0b, NPATH);
  hipMemsetAsync(cnt, 0, NRK * 4, stream);
  hipMemsetAsync(fill, 0, NRK * 4, stream);
  k_count<<<dim3(NE / 256), blk, 0, stream>>>(edge_idx, edge_type, cnt);
  k_scan1<<<dim3(NSB), blk, 0, stream>>>(cnt, bsum);
  k_scan2<<<dim3(1), dim3(1024), 0, stream>>>(bsum, bscan);
  k_scan3<<<dim3(NSB), blk, 0, stream>>>(cnt, bscan, off);
  k_fill<<<dim3(NE / 256), blk, 0, stream>>>(edge_idx, edge_type, off, fill, srcs);
  k_troot<<<dim3((IN1 * HDIM) / 256), blk, 0, stream>>>(root1, Wb1, IN1);
  k_troot<<<dim3((HDIM * HDIM) / 256), blk, 0, stream>>>(root2, Wb2, HDIM);
  k_wbasis<<<dim3((BB * HDIM * IN1) / 256), blk, 0, stream>>>(basis1, Wb1 + 256 * IN1, IN1);
  k_wbasis<<<dim3((BB * HDIM * HDIM) / 256), blk, 0, stream>>>(basis2, Wb2 + 256 * HDIM, HDIM);

  const int gAll = (NN + 63) / 64;         // 782 blocks: whole graph, one dispatch
  const int aAll = (NN + 3) / 4;           // 12500 agg blocks

  // ---- conv1: ONE full-graph agg + ONE 782-block GEMM (r15 proven: 123us) ----
  k_aggb<<<dim3(aAll), blk, 0, stream>>>(srcs, off, cnt, comp1, x0b, aggB, IN1, 0, NN);
  k_gemm<<<dim3(gAll), blk, 0, stream>>>(x0b, aggB, Wb1, bias1, att1, h1b, IN1, 0, NN);

  if (full2) {
    // ---- conv2: same single-dispatch structure ----
    k_aggb<<<dim3(aAll), blk, 0, stream>>>(srcs, off, cnt, comp2, h1b, aggB, HDIM, 0, NN);
    k_gemm<<<dim3(gAll), blk, 0, stream>>>(h1b, aggB, Wb2, bias2, att2, h2b, HDIM, 0, NN);
  } else {
    // ---- conv2 fallback: round-15 2-chunk serial ----
    const int n1 = CH0, n2 = NN - CH0;
    const int g1 = n1 / 64, g2 = (n2 + 63) / 64;
    k_aggb<<<dim3(n1 / 4), blk, 0, stream>>>(srcs, off, cnt, comp2, h1b, aggB, HDIM, 0, n1);
    k_gemm<<<dim3(g1), blk, 0, stream>>>(h1b, aggB, Wb2, bias2, att2, h2b, HDIM, 0, CH0);
    k_aggb<<<dim3((n2 + 3) / 4), blk, 0, stream>>>(srcs, off, cnt, comp2, h1b, aggB, HDIM, CH0, n2);
    k_gemm<<<dim3(g2), blk, 0, stream>>>(h1b, aggB, Wb2, bias2, att2, h2b, HDIM, CH0, NN);
  }

  // ---- prediction head ----
  k_pred<<<dim3((NN * 12 + 255) / 256), blk, 0, stream>>>(h2b, pred_w, pred_b, out);
}

// Round 17
// 768.689 us; speedup vs baseline: 1.0114x; 1.0114x over previous
//
#include <hip/hip_runtime.h>
#include <cstddef>

// ---- problem constants ----
#define NN     50000
#define NE     800000
#define IND    128
#define EMBD   64
#define IN1    192     // IND + EMBD
#define HDIM   256
#define RR     12
#define BB     8
#define NGENE  20000
#define NPATH  2000
#define NRK    (RR * NN)               // 600000 segment keys (dst-major: dst*RR+rel)
#define SCB    1024
#define NSB    ((NRK + SCB - 1) / SCB) // 586
#define CH0    25088                   // conv2 fallback chunk0 rows [0,CH0)

typedef __attribute__((ext_vector_type(8))) short short8;
typedef __attribute__((ext_vector_type(4))) float f32x4;
typedef unsigned short ushortT;
typedef __attribute__((address_space(3))) void lds_void;
typedef __attribute__((address_space(1))) const void glb_void;

__device__ __forceinline__ float bu2f(unsigned short u) {
  unsigned int x = ((unsigned int)u) << 16;
  return __builtin_bit_cast(float, x);
}
__device__ __forceinline__ unsigned short f2bu(float f) {
  unsigned int x = __builtin_bit_cast(unsigned int, f);
  unsigned int r = (x + 0x7fffu + ((x >> 16) & 1u)) >> 16;
  return (unsigned short)r;
}

// Global A-layout swizzle: within each 64-elem k-group, 8-elem chunk ch of row g
// is stored at chunk position ch ^ (g & 7). GEMM DMA-stages raw row slices, so the
// LDS tile arrives pre-swizzled (conflict-free ds_read_b128 frag loads).

// ---------- build x0 = [x | 0] bf16, swizzled ----------
__global__ void k_build_x0(const float* __restrict__ x, ushortT* __restrict__ x0) {
  int t = blockIdx.x * 256 + threadIdx.x;
  if (t >= NN * IN1) return;
  int n = t / IN1, i = t - n * IN1;
  float v = (i < IND) ? x[(size_t)n * IND + i] : 0.0f;
  int kt = i >> 6, ch = (i >> 3) & 7, off = i & 7;
  x0[(size_t)n * IN1 + kt * 64 + ((ch ^ (n & 7)) * 8) + off] = f2bu(v);
}

__global__ void k_add_emb(const int* __restrict__ idx, const float* __restrict__ emb,
                          ushortT* __restrict__ x0, int count) {
  int t = blockIdx.x * 256 + threadIdx.x;
  if (t >= count * EMBD) return;
  int g = t / EMBD, j = t - g * EMBD;
  int n = idx[g];
  int ch = (j >> 3) & 7, off = j & 7;
  x0[(size_t)n * IN1 + 128 + ((ch ^ (n & 7)) * 8) + off] = f2bu(emb[t]);
}

// ---------- per-(dst,rel) edge counts (dst-major keys) ----------
__global__ void k_count(const int* __restrict__ ei, const int* __restrict__ et,
                        int* __restrict__ cnt) {
  int e = blockIdx.x * 256 + threadIdx.x;
  if (e >= NE) return;
  atomicAdd(&cnt[ei[NE + e] * RR + et[e]], 1);
}

// ---------- 3-kernel exclusive scan ----------
__global__ __launch_bounds__(256) void k_scan1(const int* __restrict__ cnt,
                                               int* __restrict__ bsum) {
  __shared__ int lds[256];
  int t = threadIdx.x;
  int base = blockIdx.x * SCB + t * 4;
  int s = 0;
#pragma unroll
  for (int j = 0; j < 4; j++) { int idx = base + j; if (idx < NRK) s += cnt[idx]; }
  lds[t] = s; __syncthreads();
  for (int d = 128; d > 0; d >>= 1) { if (t < d) lds[t] += lds[t + d]; __syncthreads(); }
  if (t == 0) bsum[blockIdx.x] = lds[0];
}

__global__ __launch_bounds__(1024) void k_scan2(const int* __restrict__ bsum,
                                                int* __restrict__ bscan) {
  __shared__ int lds[1024];
  int t = threadIdx.x;
  int v = (t < NSB) ? bsum[t] : 0;
  lds[t] = v; __syncthreads();
  for (int d = 1; d < 1024; d <<= 1) {
    int add = (t >= d) ? lds[t - d] : 0; __syncthreads();
    lds[t] += add; __syncthreads();
  }
  if (t < NSB) bscan[t] = lds[t] - v;
}

__global__ __launch_bounds__(256) void k_scan3(const int* __restrict__ cnt,
                                               const int* __restrict__ bscan,
                                               int* __restrict__ off) {
  __shared__ int lds[256];
  int t = threadIdx.x;
  int base = blockIdx.x * SCB + t * 4;
  int v[4]; int s = 0;
#pragma unroll
  for (int j = 0; j < 4; j++) { int idx = base + j; v[j] = (idx < NRK) ? cnt[idx] : 0; s += v[j]; }
  lds[t] = s; __syncthreads();
  for (int d = 1; d < 256; d <<= 1) {
    int add = (t >= d) ? lds[t - d] : 0; __syncthreads();
    lds[t] += add; __syncthreads();
  }
  int ex = lds[t] - s + bscan[blockIdx.x];
#pragma unroll
  for (int j = 0; j < 4; j++) {
    int idx = base + j;
    if (idx < NRK) { off[idx] = ex; ex += v[j]; }
  }
}

__global__ void k_fill(const int* __restrict__ ei, const int* __restrict__ et,
                       const int* __restrict__ off, int* __restrict__ fill,
                       int* __restrict__ srcs) {
  int e = blockIdx.x * 256 + threadIdx.x;
  if (e >= NE) return;
  int key = ei[NE + e] * RR + et[e];
  int pos = off[key] + atomicAdd(&fill[key], 1);
  srcs[pos] = ei[e];
}

// ---------- Wb[b][o][i] = bf16(basis[b,i,o]) (linear layout, follows root seg) ----------
__global__ void k_wbasis(const float* __restrict__ basis, ushortT* __restrict__ W,
                         int in_dim) {
  int t = blockIdx.x * 256 + threadIdx.x;
  int total = BB * HDIM * in_dim;
  if (t >= total) return;
  int i = t % in_dim;
  int o = (t / in_dim) & 255;
  int b = t / (in_dim * 256);
  W[t] = f2bu(basis[((size_t)b * in_dim + i) * HDIM + o]);
}

__global__ void k_troot(const float* __restrict__ root, ushortT* __restrict__ rt,
                        int in_dim) {
  int t = blockIdx.x * 256 + threadIdx.x;
  if (t >= in_dim * HDIM) return;
  int i = t % in_dim, o = t / in_dim;
  rt[t] = f2bu(root[(size_t)i * HDIM + o]);
}

// ---------- basis-space aggregation: one wave per dst (round-10 proven version) ----
// Batched first-2-edges gather (24 independent loads), serial >=3-edge tails.
// Dispatch-floor-bound: one 50K-dst dispatch costs ~same as one 25K-dst dispatch
// (r15/16: full-graph agg absent from top-5, i.e. <123us, vs 2x88 chunked).
__global__ __launch_bounds__(256) void k_aggb(const int* __restrict__ srcs,
                                              const int* __restrict__ off,
                                              const int* __restrict__ cnt,
                                              const float* __restrict__ comp,
                                              const ushortT* __restrict__ xin,
                                              ushortT* __restrict__ aggB,
                                              int in_dim, int row0, int nrows) {
  int wv = threadIdx.x >> 6;
  int lane = threadIdx.x & 63;
  int li = blockIdx.x * 4 + wv;          // chunk-local dst index
  if (li >= nrows) return;
  int dst = row0 + li;
  bool act = lane * 4 < in_dim;
  int kt = lane >> 4, chl = (lane >> 1) & 7, offh = (lane & 1) * 4;
  int kbase = kt * 64 + offh;

  auto gaddr = [&](int s) {
    return (const ushort4*)(xin + (size_t)s * in_dim + kbase + ((chl ^ (s & 7)) * 8));
  };

  int beg[RR], n[RR];
#pragma unroll
  for (int rl = 0; rl < RR; rl++) {
    beg[rl] = off[dst * RR + rl];
    n[rl]   = cnt[dst * RR + rl];
  }

  int sa[RR], sb[RR];
#pragma unroll
  for (int rl = 0; rl < RR; rl++) {
    sa[rl] = (n[rl] > 0) ? srcs[beg[rl]] : 0;
    sb[rl] = (n[rl] > 1) ? srcs[beg[rl] + 1] : 0;
  }

  ushort4 va[RR], vb[RR];
  if (act) {
#pragma unroll
    for (int rl = 0; rl < RR; rl++) va[rl] = *gaddr(sa[rl]);
#pragma unroll
    for (int rl = 0; rl < RR; rl++) vb[rl] = *gaddr(sb[rl]);
  }

  float acc[BB][4];
#pragma unroll
  for (int b = 0; b < BB; b++)
#pragma unroll
    for (int e = 0; e < 4; e++) acc[b][e] = 0.f;

#pragma unroll
  for (int rl = 0; rl < RR; rl++) {
    int ne = n[rl];
    if (ne == 0) continue;
    float s0 = 0.f, s1 = 0.f, s2 = 0.f, s3 = 0.f;
    if (act) {
      s0 = bu2f(va[rl].x); s1 = bu2f(va[rl].y); s2 = bu2f(va[rl].z); s3 = bu2f(va[rl].w);
      if (ne > 1) {
        s0 += bu2f(vb[rl].x); s1 += bu2f(vb[rl].y);
        s2 += bu2f(vb[rl].z); s3 += bu2f(vb[rl].w);
      }
    }
    for (int p = 2; p < ne; p++) {          // rare tail (~15% of relations)
      int s = srcs[beg[rl] + p];
      if (act) {
        ushort4 v = *gaddr(s);
        s0 += bu2f(v.x); s1 += bu2f(v.y); s2 += bu2f(v.z); s3 += bu2f(v.w);
      }
    }
    float wn = 1.0f / (float)ne;
#pragma unroll
    for (int b = 0; b < BB; b++) {
      float cb = comp[rl * BB + b] * wn;
      acc[b][0] += cb * s0; acc[b][1] += cb * s1;
      acc[b][2] += cb * s2; acc[b][3] += cb * s3;
    }
  }

  if (act) {
    size_t base = (size_t)li * BB * in_dim;
    int swz = (chl ^ (dst & 7)) * 8;
#pragma unroll
    for (int b = 0; b < BB; b++) {
      ushort4 o;
      o.x = f2bu(acc[b][0]); o.y = f2bu(acc[b][1]);
      o.z = f2bu(acc[b][2]); o.w = f2bu(acc[b][3]);
      *(ushort4*)(aggB + base + (size_t)b * in_dim + kbase + swz) = o;
    }
  }
}

// ---------- single-pass 9-segment MFMA GEMM, 64x256 tile ----------
// 256 threads = 4 waves, wave wc owns cols [wc*64,wc*64+64) (== head wc), 64 rows.
// W fragments REGISTER-double-buffered, loaded one tile ahead at the TOP of the
// iteration; wait is vmcnt(10). Never vmcnt(0) in the loop.
// Cost model (r10/r15 measured): dur ~ max(87us, ~6ns x blocks x K-steps) once
// >=1.5 blocks/CU. Full-graph single dispatches beat chunked pairs. LDS 33.8KB ->
// 4 blocks/CU max; 782 blocks = 3.05/CU, fully co-resident.
__global__ __launch_bounds__(256, 2) void k_gemm(const ushortT* __restrict__ xin,
                                                 const ushortT* __restrict__ aggB,
                                                 const ushortT* __restrict__ W,
                                                 const float* __restrict__ bias,
                                                 const float* __restrict__ att,
                                                 ushortT* __restrict__ hout,
                                                 int in_dim, int row0, int row1) {
  __shared__ ushortT As[4][64 * 64];
  __shared__ float sm[64][4];
  const int tid = threadIdx.x;
  const int bm = row0 + blockIdx.x * 64;
  const int wv = tid >> 6, l = tid & 63;
  const int wc = wv;                       // head / col-group
  const int lm = l & 15, lq = l >> 4;
  const int nkt = in_dim >> 6;
  const int totKt = 9 * nkt;

  f32x4 acc[4][4];
#pragma unroll
  for (int mt = 0; mt < 4; mt++)
#pragma unroll
    for (int nt = 0; nt < 4; nt++) acc[mt][nt] = (f32x4){0.f, 0.f, 0.f, 0.f};

  struct WF { short8 f[2][4]; };           // [ks][nt], all indices compile-time
  WF w0, w1;

  auto stage = [&](int buf, int seg, int kt) {
#pragma unroll
    for (int j = 0; j < 2; j++) {
      int r = wv * 16 + j * 8;                 // wave-uniform LDS row base
      int g = bm + r + (l >> 3); if (g >= row1) g = row1 - 1;
      const ushortT* gp;
      if (seg == 0) gp = xin + (size_t)g * in_dim + kt * 64 + (l & 7) * 8;
      else gp = aggB + ((size_t)(g - row0) * 8 + (seg - 1)) * in_dim + kt * 64 + (l & 7) * 8;
      ushortT* lp = &As[buf][r * 64];
      __builtin_amdgcn_global_load_lds((glb_void*)gp, (lds_void*)lp, 16, 0, 0);
    }
  };

  auto loadW = [&](WF& wd, int seg, int kt) {
    const ushortT* wt = W + (size_t)(wc * 64 + lm) * in_dim +
                        (size_t)seg * 256 * in_dim + kt * 64 + lq * 8;
#pragma unroll
    for (int nt = 0; nt < 4; nt++) {
      wd.f[0][nt] = *(const short8*)(wt + (size_t)nt * 16 * in_dim);
      wd.f[1][nt] = *(const short8*)(wt + (size_t)nt * 16 * in_dim + 32);
    }
  };

  auto mfmaT = [&](int buf, const WF& wf) {
#pragma unroll
    for (int ks = 0; ks < 2; ks++) {
      short8 af[4];
#pragma unroll
      for (int mt = 0; mt < 4; mt++) {
        int ar = mt * 16 + lm;
        af[mt] = *(const short8*)(&As[buf][ar * 64 + (((ks * 4) + lq) ^ (ar & 7)) * 8]);
      }
#pragma unroll
      for (int mt = 0; mt < 4; mt++)
#pragma unroll
        for (int nt = 0; nt < 4; nt++)
          acc[mt][nt] = __builtin_amdgcn_mfma_f32_16x16x32_bf16(af[mt], wf.f[ks][nt],
                                                                acc[mt][nt], 0, 0, 0);
    }
  };

  // tile counters with clamp-at-last (keeps vmcnt literal + issue count uniform)
  int segS = 0, ktS = 0;                   // next stage tile
  int segW = 0, ktW = 0;                   // next W tile
  auto bumpC = [&](int& s, int& k) {
    if (++k == nkt) { k = 0; if (++s == 9) { s = 8; k = nkt - 1; } }
  };

  auto body = [&](int t, WF& wuse, WF& wload) {
    loadW(wload, segW, ktW); bumpC(segW, ktW);     // W_{t+1}: FIRST issue this iter
    asm volatile("s_waitcnt vmcnt(10)" ::: "memory"); // W_t + stage_t landed
    __builtin_amdgcn_s_barrier();
    __builtin_amdgcn_sched_barrier(0);
    stage((t + 3) & 3, segS, ktS); bumpC(segS, ktS); // safe: all waves past mfma(t-1)
    mfmaT(t & 3, wuse);
  };

  // prologue: stage tiles 0,1,2; preload W tile 0
  stage(0, segS, ktS); bumpC(segS, ktS);
  stage(1, segS, ktS); bumpC(segS, ktS);
  stage(2, segS, ktS); bumpC(segS, ktS);
  loadW(w0, segW, ktW); bumpC(segW, ktW);

  int t = 0;
  for (; t + 1 < totKt; t += 2) {
    body(t, w0, w1);
    body(t + 1, w1, w0);
  }
  if (t < totKt) body(t, w0, w1);
  asm volatile("s_waitcnt vmcnt(0)" ::: "memory");
  __syncthreads();

  // ---- epilogue: bias, fused head-softmax attention, swizzled bf16 store ----
  float bv[4];
#pragma unroll
  for (int nt = 0; nt < 4; nt++) bv[nt] = bias[wc * 64 + nt * 16 + lm];
#pragma unroll
  for (int mt = 0; mt < 4; mt++)
#pragma unroll
    for (int nt = 0; nt < 4; nt++)
#pragma unroll
      for (int r = 0; r < 4; r++) acc[mt][nt][r] += bv[nt];

  float av[4];
#pragma unroll
  for (int nt = 0; nt < 4; nt++) av[nt] = att[wc * 64 + nt * 16 + lm];
#pragma unroll
  for (int mt = 0; mt < 4; mt++) {
    float sr[4];
#pragma unroll
    for (int r = 0; r < 4; r++)
      sr[r] = acc[mt][0][r] * av[0] + acc[mt][1][r] * av[1] +
              acc[mt][2][r] * av[2] + acc[mt][3][r] * av[3];
#pragma unroll
    for (int o = 1; o <= 8; o <<= 1) {
#pragma unroll
      for (int r = 0; r < 4; r++) sr[r] += __shfl_xor(sr[r], o, 64);
    }
    if (lm == 0) {
#pragma unroll
      for (int r = 0; r < 4; r++) sm[mt * 16 + lq * 4 + r][wc] = sr[r];
    }
  }
  __syncthreads();
  if (tid < 64) {
    float s0 = sm[tid][0], s1 = sm[tid][1], s2 = sm[tid][2], s3 = sm[tid][3];
    float mx = fmaxf(fmaxf(s0, s1), fmaxf(s2, s3));
    float e0 = __expf(s0 - mx), e1 = __expf(s1 - mx), e2 = __expf(s2 - mx), e3 = __expf(s3 - mx);
    float inv = 1.0f / (e0 + e1 + e2 + e3);
    sm[tid][0] = e0 * inv; sm[tid][1] = e1 * inv; sm[tid][2] = e2 * inv; sm[tid][3] = e3 * inv;
  }
  __syncthreads();
#pragma unroll
  for (int mt = 0; mt < 4; mt++) {
#pragma unroll
    for (int r = 0; r < 4; r++) {
      int rl = mt * 16 + lq * 4 + r;
      int row = bm + rl;
      if (row >= row1) continue;
      float al = sm[rl][wc];
      ushortT* op = hout + (size_t)row * HDIM + wc * 64;   // kt-group == head == wc
      int key = row & 7;
#pragma unroll
      for (int nt = 0; nt < 4; nt++) {
        int ci = nt * 16 + lm;
        op[(((ci >> 3) ^ key) * 8) + (ci & 7)] = f2bu(acc[mt][nt][r] * al);
      }
    }
  }
}

// ---------- prediction head: h is swizzled; un-swizzle on read ----------
__global__ void k_pred(const ushortT* __restrict__ h, const float* __restrict__ w,
                       const float* __restrict__ b, float* __restrict__ out) {
  int t = blockIdx.x * 256 + threadIdx.x;
  if (t >= NN * 12) return;
  int n = t / 12, j = t - n * 12;
  float acc = b[j];
  const ushortT* hp = h + (size_t)n * HDIM;
  int key = n & 7;
#pragma unroll
  for (int kt = 0; kt < 4; kt++)
#pragma unroll
    for (int cs = 0; cs < 8; cs++) {
      int ch = cs ^ key;                 // logical chunk for stored chunk cs
      int kb = kt * 64 + ch * 8;
      const ushortT* hh = hp + kt * 64 + cs * 8;
#pragma unroll
      for (int o = 0; o < 8; o++) acc += bu2f(hh[o]) * w[(kb + o) * 12 + j];
    }
  out[t] = acc;
}

extern "C" void kernel_launch(void* const* d_in, const int* in_sizes, int n_in,
                              void* d_out, int out_size, void* d_ws, size_t ws_size,
                              hipStream_t stream) {
  const float* x         = (const float*)d_in[0];
  const int*   edge_idx  = (const int*)d_in[1];
  const int*   edge_type = (const int*)d_in[2];
  const int*   gene_idx  = (const int*)d_in[3];
  const int*   path_idx  = (const int*)d_in[4];
  const float* gene_emb  = (const float*)d_in[5];
  const float* path_emb  = (const float*)d_in[6];
  const float* comp1     = (const float*)d_in[7];
  const float* basis1    = (const float*)d_in[8];
  const float* root1     = (const float*)d_in[9];
  const float* bias1     = (const float*)d_in[10];
  const float* att1      = (const float*)d_in[11];
  const float* comp2     = (const float*)d_in[12];
  const float* basis2    = (const float*)d_in[13];
  const float* root2     = (const float*)d_in[14];
  const float* bias2     = (const float*)d_in[15];
  const float* att2      = (const float*)d_in[16];
  const float* pred_w    = (const float*)d_in[17];
  const float* pred_b    = (const float*)d_in[18];
  float* out = (float*)d_out;

  // ---- dynamic workspace layout ----
  // Round-16 missed the full-conv2 path by 37KB if ws = 256 MiB (268,435,456):
  // the threshold was 268,472,576 because fill/bsum/bscan sat in the persistent
  // tail. They are SETUP-ONLY (dead before the first k_aggb write), so overlay
  // them into the aggB region (r12-proven). New full-path requirement:
  //   head 51,200,000 + aggB 204,800,000 + tail 10,064,384 = 266,064,384 B.
  const size_t AGG_FULL2 = (size_t)NN * BB * HDIM * 2;   // 204,800,000
  const size_t AGG_CONV1 = (size_t)NN * BB * IN1 * 2;    // 153,600,000
  const size_t TAIL      = 884736 + 1179648 + 2400000 + 2400000 + 3200000; // 10,064,384
  bool full2 = ws_size >= (size_t)51200000 + AGG_FULL2 + TAIL;  // 266,064,384
  size_t aggRegion = full2 ? AGG_FULL2 : AGG_CONV1;

  char* ws = (char*)d_ws;
  ushortT* x0b   = (ushortT*)(ws);                   // 19.2 MB (h2b overlays later)
  ushortT* h2b   = (ushortT*)(ws);                   // 25.6 MB (x0b dead by then)
  ushortT* h1b   = (ushortT*)(ws + 25600000);        // 25,600,000
  ushortT* aggB  = (ushortT*)(ws + 51200000);        // aggRegion bytes
  char* tail = ws + 51200000 + aggRegion;
  ushortT* Wb1   = (ushortT*)(tail);                 // 884,736
  ushortT* Wb2   = (ushortT*)(tail + 884736);        // 1,179,648
  int*     cnt   = (int*)(tail + 2064384);           // 2,400,000
  int*     off   = (int*)(tail + 4464384);           // 2,400,000
  int*     srcs  = (int*)(tail + 6864384);           // 3,200,000
  // setup-only scratch overlaid into aggB region (dead before first k_aggb):
  int*     fill  = (int*)(ws + 51200000);            // 2,400,000
  int*     bsum  = (int*)(ws + 53600000);            // 4 KB
  int*     bscan = (int*)(ws + 53604096);            // 4 KB

  dim3 blk(256);

  // ---- stage 0: features + CSR build + weight prep ----
  k_build_x0<<<dim3((NN * IN1) / 256), blk, 0, stream>>>(x, x0b);
  k_add_emb<<<dim3((NGENE * EMBD) / 256), blk, 0, stream>>>(gene_idx, gene_emb, x0b, NGENE);
  k_add_emb<<<dim3((NPATH * EMBD) / 256), blk, 0, stream>>>(path_idx, path_emb, x0b, NPATH);
  hipMemsetAsync(cnt, 0, NRK * 4, stream);
  hipMemsetAsync(fill, 0, NRK * 4, stream);
  k_count<<<dim3(NE / 256), blk, 0, stream>>>(edge_idx, edge_type, cnt);
  k_scan1<<<dim3(NSB), blk, 0, stream>>>(cnt, bsum);
  k_scan2<<<dim3(1), dim3(1024), 0, stream>>>(bsum, bscan);
  k_scan3<<<dim3(NSB), blk, 0, stream>>>(cnt, bscan, off);
  k_fill<<<dim3(NE / 256), blk, 0, stream>>>(edge_idx, edge_type, off, fill, srcs);
  k_troot<<<dim3((IN1 * HDIM) / 256), blk, 0, stream>>>(root1, Wb1, IN1);
  k_troot<<<dim3((HDIM * HDIM) / 256), blk, 0, stream>>>(root2, Wb2, HDIM);
  k_wbasis<<<dim3((BB * HDIM * IN1) / 256), blk, 0, stream>>>(basis1, Wb1 + 256 * IN1, IN1);
  k_wbasis<<<dim3((BB * HDIM * HDIM) / 256), blk, 0, stream>>>(basis2, Wb2 + 256 * HDIM, HDIM);

  const int gAll = (NN + 63) / 64;         // 782 blocks: whole graph, one dispatch
  const int aAll = (NN + 3) / 4;           // 12500 agg blocks

  // ---- conv1: ONE full-graph agg + ONE 782-block GEMM (r15 proven: 123us) ----
  k_aggb<<<dim3(aAll), blk, 0, stream>>>(srcs, off, cnt, comp1, x0b, aggB, IN1, 0, NN);
  k_gemm<<<dim3(gAll), blk, 0, stream>>>(x0b, aggB, Wb1, bias1, att1, h1b, IN1, 0, NN);

  if (full2) {
    // ---- conv2: same single-dispatch structure ----
    k_aggb<<<dim3(aAll), blk, 0, stream>>>(srcs, off, cnt, comp2, h1b, aggB, HDIM, 0, NN);
    k_gemm<<<dim3(gAll), blk, 0, stream>>>(h1b, aggB, Wb2, bias2, att2, h2b, HDIM, 0, NN);
  } else {
    // ---- conv2 fallback: round-15 2-chunk serial ----
    const int n1 = CH0, n2 = NN - CH0;
    const int g1 = n1 / 64, g2 = (n2 + 63) / 64;
    k_aggb<<<dim3(n1 / 4), blk, 0, stream>>>(srcs, off, cnt, comp2, h1b, aggB, HDIM, 0, n1);
    k_gemm<<<dim3(g1), blk, 0, stream>>>(h1b, aggB, Wb2, bias2, att2, h2b, HDIM, 0, CH0);
    k_aggb<<<dim3((n2 + 3) / 4), blk, 0, stream>>>(srcs, off, cnt, comp2, h1b, aggB, HDIM, CH0, n2);
    k_gemm<<<dim3(g2), blk, 0, stream>>>(h1b, aggB, Wb2, bias2, att2, h2b, HDIM, CH0, NN);
  }

  // ---- prediction head ----
  k_pred<<<dim3((NN * 12 + 255) / 256), blk, 0, stream>>>(h2b, pred_w, pred_b, out);
}